// Round 15
// baseline (268.914 us; speedup 1.0000x reference)
//
#include <hip/hip_runtime.h>
#include <stdint.h>

#define BB 2
#define HH 16
#define NN 2048
#define DD 128
#define EE 2048

typedef short s16x8 __attribute__((ext_vector_type(8)));
typedef float fx4 __attribute__((ext_vector_type(4)));

static __device__ __forceinline__ unsigned short f2bf(float f) {
  unsigned u = __builtin_bit_cast(unsigned, f);
  u += 0x7fffu + ((u >> 16) & 1u);
  return (unsigned short)(u >> 16);
}
static __device__ __forceinline__ float bf2f(unsigned short h) {
  unsigned u = ((unsigned)h) << 16;
  return __builtin_bit_cast(float, u);
}
static __device__ __forceinline__ void gload_lds16(const void* g, void* l) {
  __builtin_amdgcn_global_load_lds(
      (const __attribute__((address_space(1))) unsigned int*)g,
      (__attribute__((address_space(3))) unsigned int*)l, 16, 0, 0);
}
static __device__ __forceinline__ unsigned cvt_pk_bf16(float lo, float hi) {
  unsigned w;
  asm("v_cvt_pk_bf16_f32 %0, %1, %2" : "=v"(w) : "v"(lo), "v"(hi));
  return w;
}

// ---------------- single fp32->bf16 convert for ALL regions ------------------
__global__ __launch_bounds__(256) void f2b_all(const float* __restrict__ x,
                                               const float* __restrict__ Wq,
                                               const float* __restrict__ Wkv,
                                               const float* __restrict__ Wo,
                                               const float* __restrict__ Wkvh,
                                               unsigned short* __restrict__ xb,
                                               unsigned short* __restrict__ wqkv,
                                               unsigned short* __restrict__ wob,
                                               unsigned short* __restrict__ wkvhb) {
  int bid = blockIdx.x;
  const float* in;
  unsigned short* out;
  int i;
  if (bid < 8192) { in = x; out = xb; i = bid * 256 + threadIdx.x; }
  else if (bid < 12288) { in = Wq; out = wqkv; i = (bid - 8192) * 256 + threadIdx.x; }
  else if (bid < 12800) { in = Wkv; out = wqkv + 4194304; i = (bid - 12288) * 256 + threadIdx.x; }
  else if (bid < 16896) { in = Wo; out = wob; i = (bid - 12800) * 256 + threadIdx.x; }
  else { in = Wkvh; out = wkvhb; i = (bid - 16896) * 256 + threadIdx.x; }
  float4 v = ((const float4*)in)[i];
  uint2 o;
  o.x = ((unsigned)f2bf(v.y) << 16) | f2bf(v.x);
  o.y = ((unsigned)f2bf(v.w) << 16) | f2bf(v.z);
  ((uint2*)out)[i] = o;
}

// ====== shared GEMM body: 128x128 tile, BK=64, swizzled staging ==============
#define GBK 64

#define GEMM_STAGE(LDSB, SRCBASE, rowb)                                        \
  _Pragma("unroll") for (int t = 0; t < 4; ++t) {                              \
    int r = wave * 32 + t * 8 + (lane >> 3);                                   \
    int ch = (lane & 7) ^ (r & 7);                                             \
    const unsigned char* src = (SRCBASE) + (size_t)r * (rowb) + ch * 16;       \
    gload_lds16(src, (void*)((LDSB) + (wave * 32 + t * 8) * 128));             \
  }

#define GEMM_LOOP_BODY                                                         \
  for (int k0 = 0; k0 < K; k0 += GBK) {                                        \
    const unsigned char* ag = Ag + (size_t)k0 * 2;                             \
    const unsigned char* bg = Bg + (size_t)k0 * 2;                             \
    __syncthreads();                                                           \
    GEMM_STAGE(Alds, ag, rowb)                                                 \
    GEMM_STAGE(Blds, bg, rowb)                                                 \
    __syncthreads();                                                           \
    _Pragma("unroll") for (int kk = 0; kk < 2; ++kk) {                         \
      s16x8 af[4], bf[4];                                                      \
      _Pragma("unroll") for (int i = 0; i < 4; ++i) {                          \
        int row = wr * 64 + i * 16 + lr;                                       \
        int chunk = (kk * 4 + g) ^ (row & 7);                                  \
        af[i] = *(const s16x8*)(Alds + row * 128 + chunk * 16);                \
      }                                                                        \
      _Pragma("unroll") for (int j = 0; j < 4; ++j) {                          \
        int row = wc * 64 + j * 16 + lr;                                       \
        int chunk = (kk * 4 + g) ^ (row & 7);                                  \
        bf[j] = *(const s16x8*)(Blds + row * 128 + chunk * 16);                \
      }                                                                        \
      _Pragma("unroll") for (int i = 0; i < 4; ++i)                            \
        _Pragma("unroll") for (int j = 0; j < 4; ++j)                          \
          acc[i][j] = __builtin_amdgcn_mfma_f32_16x16x32_bf16(af[i], bf[j],    \
                                                              acc[i][j], 0, 0, 0); \
    }                                                                          \
  }

#define GEMM_PROLOG                                                            \
  __shared__ alignas(16) unsigned char Alds[128 * 128];                        \
  __shared__ alignas(16) unsigned char Blds[128 * 128];                        \
  const int tid = threadIdx.x;                                                 \
  const int wave = tid >> 6, lane = tid & 63;                                  \
  const int g = lane >> 4, lr = lane & 15;                                     \
  const int mtiles = M / 128;                                                  \
  const int mt = blockIdx.x % mtiles, nt = blockIdx.x / mtiles;                \
  const int m0 = mt * 128, n0 = nt * 128;                                      \
  const int wr = wave >> 1, wc = wave & 1;                                     \
  fx4 acc[4][4];                                                               \
  _Pragma("unroll") for (int i = 0; i < 4; ++i)                                \
    _Pragma("unroll") for (int j = 0; j < 4; ++j)                              \
      acc[i][j] = (fx4){0.f, 0.f, 0.f, 0.f};                                   \
  const unsigned char* Ag = (const unsigned char*)(A + (size_t)m0 * K);        \
  const unsigned char* Bg = (const unsigned char*)(B + (size_t)n0 * K);        \
  const size_t rowb = (size_t)K * 2;

// ---------------- out GEMM: fp32 C --------------------------------------------
__global__ __launch_bounds__(256) void gemm_out(const unsigned short* __restrict__ A,
                                                const unsigned short* __restrict__ B,
                                                float* __restrict__ Cf,
                                                int M, int N, int K) {
  GEMM_PROLOG
  GEMM_LOOP_BODY
#pragma unroll
  for (int i = 0; i < 4; ++i) {
    int row = m0 + wr * 64 + i * 16 + 4 * g;
#pragma unroll
    for (int j = 0; j < 4; ++j) {
      int col = n0 + wc * 64 + j * 16 + lr;
#pragma unroll
      for (int r = 0; r < 4; ++r)
        Cf[(size_t)(row + r) * N + col] = acc[i][j][r];
    }
  }
}

// ---------------- qkv GEMM with fused RoPE-q epilogue ------------------------
__global__ __launch_bounds__(256) void gemm_qkv(const unsigned short* __restrict__ A,
                                                const unsigned short* __restrict__ B,
                                                unsigned short* __restrict__ qrope,
                                                unsigned short* __restrict__ kvb,
                                                int M, int N, int K) {
  GEMM_PROLOG
  GEMM_LOOP_BODY
#pragma unroll
  for (int j = 0; j < 4; ++j) {
    int col = n0 + wc * 64 + j * 16 + lr;
    if (col < 2048) {
      int hh = col >> 7, d = col & 127;
      float invf = __expf(-0.14391156831212787f * (float)(d >> 1));
      int par = d & 1;
#pragma unroll
      for (int i = 0; i < 4; ++i) {
#pragma unroll
        for (int r = 0; r < 4; ++r) {
          int row = m0 + wr * 64 + i * 16 + 4 * g + r;
          int n = row & (NN - 1), bq = row >> 11;
          float self = acc[i][j][r];
          float other = __shfl_xor(self, 1);
          float sn, cs;
          __sincosf((float)n * invf, &sn, &cs);
          float a = self * cs, bt = other * sn;
          float o = par ? (a + bt) : (a - bt);
          qrope[((size_t)(bq * HH + hh) * NN + n) * DD + d] = f2bf(o);
        }
      }
    } else {
      int c2 = col - 2048;
#pragma unroll
      for (int i = 0; i < 4; ++i) {
#pragma unroll
        for (int r = 0; r < 4; ++r) {
          int row = m0 + wr * 64 + i * 16 + 4 * g + r;
          kvb[(size_t)row * 256 + c2] = f2bf(acc[i][j][r]);
        }
      }
    }
  }
}

// ---------------- kvh projection via MFMA -> packed [b][h][n]{k,v} ----------
__global__ __launch_bounds__(256) void kvh_mfma(const unsigned short* __restrict__ X,
                                                const unsigned short* __restrict__ Wb,
                                                float* __restrict__ out) {
  const int tid = threadIdx.x;
  const int wave = tid >> 6, lane = tid & 63;
  const int g = lane >> 4, lr = lane & 15;
  const int rowbase = blockIdx.x * 32 + (wave & 1) * 16;
  const int colbase = (wave >> 1) * 16;

  const unsigned short* xr = X + (size_t)(rowbase + lr) * EE + 8 * g;
  const unsigned short* wr = Wb + (size_t)(colbase + lr) * EE + 8 * g;

  fx4 acc = (fx4){0.f, 0.f, 0.f, 0.f};
#pragma unroll 8
  for (int k0 = 0; k0 < EE; k0 += 32) {
    s16x8 a = *(const s16x8*)(xr + k0);
    s16x8 b = *(const s16x8*)(wr + k0);
    acc = __builtin_amdgcn_mfma_f32_16x16x32_bf16(a, b, acc, 0, 0, 0);
  }
  const int j = colbase + lr;
  const int head = j & 15, sel = j >> 4;
#pragma unroll
  for (int r = 0; r < 4; ++r) {
    int m = rowbase + 4 * g + r;
    int b = m >> 11, n = m & (NN - 1);
    out[(((size_t)(b * HH + head)) * NN + n) * 2 + sel] = acc[r];
  }
}

// ---------------- RoPE on shared k (kvb rows stride 256, cols 0..127) --------
__global__ __launch_bounds__(256) void rope_k(const unsigned short* __restrict__ kv,
                                              unsigned short* __restrict__ ko) {
  int idx = blockIdx.x * 256 + threadIdx.x;
  int i = idx & 63;
  int bn = idx >> 6;
  int n = bn & (NN - 1);
  unsigned v = *(const unsigned*)(kv + (size_t)bn * 256 + 2 * i);
  float x1 = bf2f((unsigned short)(v & 0xffff));
  float x2 = bf2f((unsigned short)(v >> 16));
  float inv = __expf(-0.14391156831212787f * (float)i);
  float ang = (float)n * inv;
  float sn, cs;
  __sincosf(ang, &sn, &cs);
  float o1 = x1 * cs - x2 * sn, o2 = x1 * sn + x2 * cs;
  unsigned ov = ((unsigned)f2bf(o2) << 16) | f2bf(o1);
  *(unsigned*)(ko + (size_t)bn * DD + 2 * i) = ov;
}

// ---------------- V transpose: kvb cols 128..255 -> vT[b][d][n] --------------
__global__ __launch_bounds__(256) void vtrans(const unsigned short* __restrict__ kv,
                                              unsigned short* __restrict__ vT) {
  __shared__ unsigned short t[64][40];
  int bx = blockIdx.x;  // 2*4*32 = 256 blocks
  int b = bx >> 7;
  int d0 = ((bx >> 5) & 3) * 32;
  int n0 = (bx & 31) * 64;
  int tid = threadIdx.x;
  {
    int i = tid >> 2;
    int c = (tid & 3) * 8;
    s16x8 v = *(const s16x8*)(kv + ((size_t)(b * NN + n0 + i)) * 256 + 128 + d0 + c);
#pragma unroll
    for (int u = 0; u < 8; ++u) t[i][c + u] = (unsigned short)v[u];
  }
  __syncthreads();
  {
    int j = tid >> 3;
    int cc = (tid & 7) * 8;
    s16x8 o;
#pragma unroll
    for (int u = 0; u < 8; ++u) o[u] = (short)t[cc + u][j];
    *(s16x8*)(vT + ((size_t)(b * DD + d0 + j)) * NN + n0 + cc) = o;
  }
}

// ------- causal flash attention: barrier-free, K/V direct from L1/L2 ---------
// K/V tiles (32KB/parity) are L1/L2-resident: no LDS staging, no __syncthreads
// in the K-loop. P is per-wave-private LDS scratch (lgkmcnt only). QB=128,
// 8 waves (2 parity groups x 4 q-waves), pairing (qp, 15-qp), combine at end.
#define QB 128
#define KB 64

__global__ __launch_bounds__(512, 2) void attn(const unsigned short* __restrict__ Q,
                                               const unsigned short* __restrict__ Kr,
                                               const unsigned short* __restrict__ VT,
                                               const float* __restrict__ KVHP,
                                               unsigned short* __restrict__ O) {
  __shared__ alignas(16) unsigned char Plds[16 * 16 * 128];  // per-(wave,qq) P; combine: O scratch
  __shared__ float2 mlbuf[4][2][16];

  const int qp = blockIdx.x;
  const int h = blockIdx.y;
  const int b = blockIdx.z;
  const int tid = threadIdx.x;
  const int wave = tid >> 6, lane = tid & 63;
  const int parity = wave >> 2, wq = wave & 3;
  const int g = lane >> 4, lr = lane & 15;
  const size_t bh = (size_t)(b * HH + h);

  const float scale2 = 0.08838834764831845f * 1.4426950408889634f;  // exp2 domain
  const unsigned short* Kb = Kr + (size_t)b * NN * DD;
  const unsigned short* VTb = VT + (size_t)b * DD * NN;
  const float2* KVp = (const float2*)KVHP + (size_t)(b * HH + h) * NN;

  float* Obuf = (float*)Plds;

  auto PHASE = [&](int qt) {
    const int qbase_w = qt * QB + wq * 32;

    s16x8 qf[2][4];
#pragma unroll
    for (int qq = 0; qq < 2; ++qq) {
      const unsigned short* qptr = Q + (bh * NN + qbase_w + qq * 16 + lr) * DD + 8 * g;
#pragma unroll
      for (int dc = 0; dc < 4; ++dc) qf[qq][dc] = *(const s16x8*)(qptr + dc * 32);
    }

    float m_run[2] = {-1e30f, -1e30f}, l_run[2] = {0.f, 0.f};
    fx4 oacc[2][8];
#pragma unroll
    for (int qq = 0; qq < 2; ++qq)
#pragma unroll
      for (int d = 0; d < 8; ++d) oacc[qq][d] = (fx4){0.f, 0.f, 0.f, 0.f};

    const int cnt = qt + 1;
    for (int i = 0; i < cnt; ++i) {
      const int key0 = (2 * i + parity) * KB;
      if (key0 > qbase_w + 31) continue;  // wave-uniform; no barriers to honor

      fx4 khv[4], vhv[4];
#pragma unroll
      for (int kb = 0; kb < 4; ++kb) {
        const float4* kp = (const float4*)(KVp + key0 + kb * 16 + 4 * g);
        float4 f0 = kp[0];
        float4 f1 = kp[1];
        khv[kb] = (fx4){f0.x * scale2, f0.z * scale2, f1.x * scale2, f1.z * scale2};
        vhv[kb] = (fx4){f0.y, f0.w, f1.y, f1.w};
      }

      // --- QK^T swapped: kf read directly from global (L1/L2-served) ---
      fx4 sacc[2][4];
#pragma unroll
      for (int qq = 0; qq < 2; ++qq)
#pragma unroll
        for (int kb = 0; kb < 4; ++kb) sacc[qq][kb] = (fx4){0.f, 0.f, 0.f, 0.f};
      __builtin_amdgcn_s_setprio(1);
#pragma unroll
      for (int kb = 0; kb < 4; ++kb) {
        const unsigned short* krow = Kb + (size_t)(key0 + kb * 16 + lr) * DD + 8 * g;
#pragma unroll
        for (int dc = 0; dc < 4; ++dc) {
          s16x8 kf = *(const s16x8*)(krow + dc * 32);
          sacc[0][kb] = __builtin_amdgcn_mfma_f32_16x16x32_bf16(kf, qf[0][dc], sacc[0][kb], 0, 0, 0);
          sacc[1][kb] = __builtin_amdgcn_mfma_f32_16x16x32_bf16(kf, qf[1][dc], sacc[1][kb], 0, 0, 0);
        }
      }
      __builtin_amdgcn_s_setprio(0);

#pragma unroll
      for (int qq = 0; qq < 2; ++qq) {
        const int qg = qbase_w + qq * 16 + lr;
        float smax = -1e30f;
        if (key0 + 63 > qbase_w + qq * 16) {
#pragma unroll
          for (int kb = 0; kb < 4; ++kb) {
#pragma unroll
            for (int r = 0; r < 4; ++r) {
              int keyg = key0 + kb * 16 + 4 * g + r;
              float s = sacc[qq][kb][r] * khv[kb][r];
              if (keyg > qg) s = -1e30f;
              sacc[qq][kb][r] = s;
              smax = fmaxf(smax, s);
            }
          }
        } else {
#pragma unroll
          for (int kb = 0; kb < 4; ++kb) {
#pragma unroll
            for (int r = 0; r < 4; ++r) {
              float s = sacc[qq][kb][r] * khv[kb][r];
              sacc[qq][kb][r] = s;
              smax = fmaxf(smax, s);
            }
          }
        }
        smax = fmaxf(smax, __shfl_xor(smax, 16));
        smax = fmaxf(smax, __shfl_xor(smax, 32));
        if (!__all(smax - m_run[qq] <= 8.0f)) {
          float mnew = fmaxf(m_run[qq], smax);
          float corr = exp2f(m_run[qq] - mnew);
          m_run[qq] = mnew;
          l_run[qq] *= corr;
          float cr[4];
#pragma unroll
          for (int r = 0; r < 4; ++r) cr[r] = __shfl(corr, 4 * g + r);
#pragma unroll
          for (int d = 0; d < 8; ++d)
#pragma unroll
            for (int r = 0; r < 4; ++r) oacc[qq][d][r] *= cr[r];
        }
        float rsum = 0.f;
#pragma unroll
        for (int kb = 0; kb < 4; ++kb) {
          float p0 = exp2f(sacc[qq][kb][0] - m_run[qq]);
          float p1 = exp2f(sacc[qq][kb][1] - m_run[qq]);
          float p2 = exp2f(sacc[qq][kb][2] - m_run[qq]);
          float p3 = exp2f(sacc[qq][kb][3] - m_run[qq]);
          rsum += (p0 + p1) + (p2 + p3);
          uint2 w;
          w.x = cvt_pk_bf16(p0 * vhv[kb][0], p1 * vhv[kb][1]);
          w.y = cvt_pk_bf16(p2 * vhv[kb][2], p3 * vhv[kb][3]);
          int chunk = (kb * 2 + (g >> 1)) ^ (lr & 7);
          *(uint2*)(Plds + (wave * 2 + qq) * 2048 + lr * 128 + chunk * 16 + (g & 1) * 8) = w;
        }
        rsum += __shfl_xor(rsum, 16);
        rsum += __shfl_xor(rsum, 32);
        l_run[qq] += rsum;
      }

      // --- PV: pa from private LDS (lgkmcnt only), vf direct from global ---
      s16x8 pa[2][2];
#pragma unroll
      for (int qq = 0; qq < 2; ++qq)
#pragma unroll
        for (int kk = 0; kk < 2; ++kk) {
          int chunk = (kk * 4 + g) ^ (lr & 7);
          pa[qq][kk] = *(const s16x8*)(Plds + (wave * 2 + qq) * 2048 + lr * 128 + chunk * 16);
        }
      __builtin_amdgcn_s_setprio(1);
#pragma unroll
      for (int dc = 0; dc < 8; ++dc) {
        const unsigned short* vrow = VTb + (size_t)(dc * 16 + lr) * NN + key0 + 8 * g;
#pragma unroll
        for (int kk = 0; kk < 2; ++kk) {
          s16x8 vf = *(const s16x8*)(vrow + kk * 32);
          oacc[0][dc] = __builtin_amdgcn_mfma_f32_16x16x32_bf16(pa[0][kk], vf, oacc[0][dc], 0, 0, 0);
          oacc[1][dc] = __builtin_amdgcn_mfma_f32_16x16x32_bf16(pa[1][kk], vf, oacc[1][dc], 0, 0, 0);
        }
      }
      __builtin_amdgcn_s_setprio(0);
    }

    // ---- combine parities (barriers only here) ----
    __syncthreads();
    if (parity == 1 && g == 0) {
#pragma unroll
      for (int qq = 0; qq < 2; ++qq)
        mlbuf[wq][qq][lr] = make_float2(m_run[qq], l_run[qq]);
    }
    __syncthreads();
    float lC[2], af0[2][4], af1[2][4];
    if (parity == 0) {
#pragma unroll
      for (int qq = 0; qq < 2; ++qq) {
        float2 ml1 = mlbuf[wq][qq][lr];
        float M = fmaxf(m_run[qq], ml1.x);
        float a0 = exp2f(m_run[qq] - M);
        float a1 = exp2f(ml1.x - M);
        lC[qq] = l_run[qq] * a0 + ml1.y * a1;
#pragma unroll
        for (int r = 0; r < 4; ++r) {
          af0[qq][r] = __shfl(a0, 4 * g + r);
          af1[qq][r] = __shfl(a1, 4 * g + r);
        }
      }
    }
#pragma unroll
    for (int dh = 0; dh < 2; ++dh) {
      if (parity == 1) {
#pragma unroll
        for (int qq = 0; qq < 2; ++qq)
#pragma unroll
          for (int dc2 = 0; dc2 < 4; ++dc2)
#pragma unroll
            for (int r = 0; r < 4; ++r)
              Obuf[wq * 2048 + (qq * 16 + 4 * g + r) * 64 + dc2 * 16 + lr] =
                  oacc[qq][dh * 4 + dc2][r];
      }
      __syncthreads();
      if (parity == 0) {
#pragma unroll
        for (int qq = 0; qq < 2; ++qq)
#pragma unroll
          for (int dc2 = 0; dc2 < 4; ++dc2)
#pragma unroll
            for (int r = 0; r < 4; ++r) {
              float o1 = Obuf[wq * 2048 + (qq * 16 + 4 * g + r) * 64 + dc2 * 16 + lr];
              oacc[qq][dh * 4 + dc2][r] =
                  oacc[qq][dh * 4 + dc2][r] * af0[qq][r] + o1 * af1[qq][r];
            }
      }
      __syncthreads();
    }
    if (parity == 0) {
#pragma unroll
      for (int qq = 0; qq < 2; ++qq) {
        float inv = 1.0f / lC[qq];
#pragma unroll
        for (int r = 0; r < 4; ++r) {
          float invr = __shfl(inv, 4 * g + r);
          int qout = qbase_w + qq * 16 + 4 * g + r;
          unsigned short* orow = O + (((size_t)b * NN + qout) * HH + h) * DD;
#pragma unroll
          for (int dc = 0; dc < 8; ++dc) orow[dc * 16 + lr] = f2bf(oacc[qq][dc][r] * invr);
        }
      }
    }
  };

  PHASE(qp);
  PHASE(15 - qp);
}

// ---------------- launch -----------------------------------------------------
extern "C" void kernel_launch(void* const* d_in, const int* in_sizes, int n_in,
                              void* d_out, int out_size, void* d_ws, size_t ws_size,
                              hipStream_t stream) {
  const float* x = (const float*)d_in[0];
  const float* Wq = (const float*)d_in[1];
  const float* Wkv = (const float*)d_in[2];
  const float* Wkvh = (const float*)d_in[3];
  const float* Wo = (const float*)d_in[4];
  float* out = (float*)d_out;
  char* ws = (char*)d_ws;

  unsigned short* xb    = (unsigned short*)(ws + 0);          // 16 MB (b*n, E)
  unsigned short* obuf  = xb;                                  // alias: x dead by attn
  unsigned short* wqkv  = (unsigned short*)(ws + 16777216);    // 9.4 MB [Wq;Wkv] bf16
  unsigned short* wob   = (unsigned short*)(ws + 26214400);    // 8 MB
  unsigned short* kvb   = (unsigned short*)(ws + 34603008);    // 2 MB (b*n, 256)
  unsigned short* vtb   = (unsigned short*)(ws + 36700160);    // 1 MB vT[b][d][n]
  unsigned short* wkvhb = (unsigned short*)(ws + 53477376);    // 128 KB Wkvh bf16
  float*          kvhb  = (float*)(ws + 53608448);             // 512 KB packed [b][h][n]{k,v}
  unsigned short* qrope = (unsigned short*)(ws + 54132736);    // 16 MB (b*h, n, d)
  unsigned short* krope = (unsigned short*)(ws + 70909952);    // 1 MB (b*n, d)

  f2b_all<<<16960, 256, 0, stream>>>(x, Wq, Wkv, Wo, Wkvh, xb, wqkv, wob, wkvhb);

  gemm_qkv<<<576, 256, 0, stream>>>(xb, wqkv, qrope, kvb, 4096, 2304, 2048);
  kvh_mfma<<<128, 256, 0, stream>>>(xb, wkvhb, kvhb);

  rope_k<<<1024, 256, 0, stream>>>(kvb, krope);
  vtrans<<<256, 256, 0, stream>>>(kvb, vtb);

  dim3 ag(8, HH, BB);
  attn<<<ag, 512, 0, stream>>>(qrope, krope, vtb, kvhb, obuf);

  gemm_out<<<512, 256, 0, stream>>>(obuf, wob, out, 4096, 2048, 2048);
}

// Round 16
// 218.836 us; speedup vs baseline: 1.2288x; 1.2288x over previous
//
#include <hip/hip_runtime.h>
#include <stdint.h>

#define BB 2
#define HH 16
#define NN 2048
#define DD 128
#define EE 2048

typedef short s16x8 __attribute__((ext_vector_type(8)));
typedef float fx4 __attribute__((ext_vector_type(4)));

static __device__ __forceinline__ unsigned short f2bf(float f) {
  unsigned u = __builtin_bit_cast(unsigned, f);
  u += 0x7fffu + ((u >> 16) & 1u);
  return (unsigned short)(u >> 16);
}
static __device__ __forceinline__ float bf2f(unsigned short h) {
  unsigned u = ((unsigned)h) << 16;
  return __builtin_bit_cast(float, u);
}
static __device__ __forceinline__ void gload_lds16(const void* g, void* l) {
  __builtin_amdgcn_global_load_lds(
      (const __attribute__((address_space(1))) unsigned int*)g,
      (__attribute__((address_space(3))) unsigned int*)l, 16, 0, 0);
}
static __device__ __forceinline__ unsigned cvt_pk_bf16(float lo, float hi) {
  unsigned w;
  asm("v_cvt_pk_bf16_f32 %0, %1, %2" : "=v"(w) : "v"(lo), "v"(hi));
  return w;
}

// ---------------- single fp32->bf16 convert for ALL regions ------------------
__global__ __launch_bounds__(256) void f2b_all(const float* __restrict__ x,
                                               const float* __restrict__ Wq,
                                               const float* __restrict__ Wkv,
                                               const float* __restrict__ Wo,
                                               const float* __restrict__ Wkvh,
                                               unsigned short* __restrict__ xb,
                                               unsigned short* __restrict__ wqkv,
                                               unsigned short* __restrict__ wob,
                                               unsigned short* __restrict__ wkvhb) {
  int bid = blockIdx.x;
  const float* in;
  unsigned short* out;
  int i;
  if (bid < 8192) { in = x; out = xb; i = bid * 256 + threadIdx.x; }
  else if (bid < 12288) { in = Wq; out = wqkv; i = (bid - 8192) * 256 + threadIdx.x; }
  else if (bid < 12800) { in = Wkv; out = wqkv + 4194304; i = (bid - 12288) * 256 + threadIdx.x; }
  else if (bid < 16896) { in = Wo; out = wob; i = (bid - 12800) * 256 + threadIdx.x; }
  else { in = Wkvh; out = wkvhb; i = (bid - 16896) * 256 + threadIdx.x; }
  float4 v = ((const float4*)in)[i];
  uint2 o;
  o.x = ((unsigned)f2bf(v.y) << 16) | f2bf(v.x);
  o.y = ((unsigned)f2bf(v.w) << 16) | f2bf(v.z);
  ((uint2*)out)[i] = o;
}

// ====== shared GEMM body: 128x128 tile, BK=64, swizzled staging ==============
#define GBK 64

#define GEMM_STAGE(LDSB, SRCBASE, rowb)                                        \
  _Pragma("unroll") for (int t = 0; t < 4; ++t) {                              \
    int r = wave * 32 + t * 8 + (lane >> 3);                                   \
    int ch = (lane & 7) ^ (r & 7);                                             \
    const unsigned char* src = (SRCBASE) + (size_t)r * (rowb) + ch * 16;       \
    gload_lds16(src, (void*)((LDSB) + (wave * 32 + t * 8) * 128));             \
  }

#define GEMM_LOOP_BODY                                                         \
  for (int k0 = 0; k0 < K; k0 += GBK) {                                        \
    const unsigned char* ag = Ag + (size_t)k0 * 2;                             \
    const unsigned char* bg = Bg + (size_t)k0 * 2;                             \
    __syncthreads();                                                           \
    GEMM_STAGE(Alds, ag, rowb)                                                 \
    GEMM_STAGE(Blds, bg, rowb)                                                 \
    __syncthreads();                                                           \
    _Pragma("unroll") for (int kk = 0; kk < 2; ++kk) {                         \
      s16x8 af[4], bf[4];                                                      \
      _Pragma("unroll") for (int i = 0; i < 4; ++i) {                          \
        int row = wr * 64 + i * 16 + lr;                                       \
        int chunk = (kk * 4 + g) ^ (row & 7);                                  \
        af[i] = *(const s16x8*)(Alds + row * 128 + chunk * 16);                \
      }                                                                        \
      _Pragma("unroll") for (int j = 0; j < 4; ++j) {                          \
        int row = wc * 64 + j * 16 + lr;                                       \
        int chunk = (kk * 4 + g) ^ (row & 7);                                  \
        bf[j] = *(const s16x8*)(Blds + row * 128 + chunk * 16);                \
      }                                                                        \
      _Pragma("unroll") for (int i = 0; i < 4; ++i)                            \
        _Pragma("unroll") for (int j = 0; j < 4; ++j)                          \
          acc[i][j] = __builtin_amdgcn_mfma_f32_16x16x32_bf16(af[i], bf[j],    \
                                                              acc[i][j], 0, 0, 0); \
    }                                                                          \
  }

#define GEMM_PROLOG(BIDX)                                                      \
  __shared__ alignas(16) unsigned char Alds[128 * 128];                        \
  __shared__ alignas(16) unsigned char Blds[128 * 128];                        \
  const int mtiles = M / 128;                                                  \
  const int mt = (BIDX) % mtiles, nt = (BIDX) / mtiles;                        \
  const int m0 = mt * 128, n0 = nt * 128;                                      \
  const int wr = wave >> 1, wc = wave & 1;                                     \
  fx4 acc[4][4];                                                               \
  _Pragma("unroll") for (int i = 0; i < 4; ++i)                                \
    _Pragma("unroll") for (int j = 0; j < 4; ++j)                              \
      acc[i][j] = (fx4){0.f, 0.f, 0.f, 0.f};                                   \
  const unsigned char* Ag = (const unsigned char*)(A + (size_t)m0 * K);        \
  const unsigned char* Bg = (const unsigned char*)(B + (size_t)n0 * K);        \
  const size_t rowb = (size_t)K * 2;

// ---------------- out GEMM: fp32 C --------------------------------------------
__global__ __launch_bounds__(256) void gemm_out(const unsigned short* __restrict__ A,
                                                const unsigned short* __restrict__ B,
                                                float* __restrict__ Cf,
                                                int M, int N, int K) {
  const int tid = threadIdx.x;
  const int wave = tid >> 6, lane = tid & 63;
  const int g = lane >> 4, lr = lane & 15;
  GEMM_PROLOG(blockIdx.x)
  GEMM_LOOP_BODY
#pragma unroll
  for (int i = 0; i < 4; ++i) {
    int row = m0 + wr * 64 + i * 16 + 4 * g;
#pragma unroll
    for (int j = 0; j < 4; ++j) {
      int col = n0 + wc * 64 + j * 16 + lr;
#pragma unroll
      for (int r = 0; r < 4; ++r)
        Cf[(size_t)(row + r) * N + col] = acc[i][j][r];
    }
  }
}

// ------ qkv GEMM (blocks 0..575) + kvh projection (blocks 576..703) ----------
// GEMM path: cols<2048 RoPE-q -> qrope[b,h,n,d]; cols>=2048 -> kvb[row][256].
// kvh path: 32 rows x 32 cols MFMA microtile -> packed kvh[b][h][n]{k,v}.
__global__ __launch_bounds__(256) void gemm_qkv(const unsigned short* __restrict__ A,
                                                const unsigned short* __restrict__ B,
                                                const unsigned short* __restrict__ Wkvhb,
                                                unsigned short* __restrict__ qrope,
                                                unsigned short* __restrict__ kvb,
                                                float* __restrict__ kvh,
                                                int M, int N, int K) {
  const int tid = threadIdx.x;
  const int wave = tid >> 6, lane = tid & 63;
  const int g = lane >> 4, lr = lane & 15;

  if (blockIdx.x >= 576) {  // ---- kvh projection path (128 blocks) ----
    const int bid2 = blockIdx.x - 576;
    const int rowbase = bid2 * 32 + (wave & 1) * 16;
    const int colbase = (wave >> 1) * 16;
    const unsigned short* xr = A + (size_t)(rowbase + lr) * EE + 8 * g;
    const unsigned short* wr2 = Wkvhb + (size_t)(colbase + lr) * EE + 8 * g;
    fx4 acc2 = (fx4){0.f, 0.f, 0.f, 0.f};
#pragma unroll 8
    for (int k0 = 0; k0 < EE; k0 += 32) {
      s16x8 a = *(const s16x8*)(xr + k0);
      s16x8 b = *(const s16x8*)(wr2 + k0);
      acc2 = __builtin_amdgcn_mfma_f32_16x16x32_bf16(a, b, acc2, 0, 0, 0);
    }
    const int j = colbase + lr;
    const int head = j & 15, sel = j >> 4;
#pragma unroll
    for (int r = 0; r < 4; ++r) {
      int m = rowbase + 4 * g + r;
      int b = m >> 11, n = m & (NN - 1);
      kvh[(((size_t)(b * HH + head)) * NN + n) * 2 + sel] = acc2[r];
    }
    return;
  }

  GEMM_PROLOG(blockIdx.x)
  GEMM_LOOP_BODY
#pragma unroll
  for (int j = 0; j < 4; ++j) {
    int col = n0 + wc * 64 + j * 16 + lr;
    if (col < 2048) {
      int hh = col >> 7, d = col & 127;
      float invf = __expf(-0.14391156831212787f * (float)(d >> 1));
      int par = d & 1;
#pragma unroll
      for (int i = 0; i < 4; ++i) {
#pragma unroll
        for (int r = 0; r < 4; ++r) {
          int row = m0 + wr * 64 + i * 16 + 4 * g + r;
          int n = row & (NN - 1), bq = row >> 11;
          float self = acc[i][j][r];
          float other = __shfl_xor(self, 1);
          float sn, cs;
          __sincosf((float)n * invf, &sn, &cs);
          float a = self * cs, bt = other * sn;
          float o = par ? (a + bt) : (a - bt);
          qrope[((size_t)(bq * HH + hh) * NN + n) * DD + d] = f2bf(o);
        }
      }
    } else {
      int c2 = col - 2048;
#pragma unroll
      for (int i = 0; i < 4; ++i) {
#pragma unroll
        for (int r = 0; r < 4; ++r) {
          int row = m0 + wr * 64 + i * 16 + 4 * g + r;
          kvb[(size_t)row * 256 + c2] = f2bf(acc[i][j][r]);
        }
      }
    }
  }
}

// ------ merged RoPE-k (blocks 0..1023) + V-transpose (blocks 1024..1279) -----
__global__ __launch_bounds__(256) void rope_vt(const unsigned short* __restrict__ kv,
                                               unsigned short* __restrict__ ko,
                                               unsigned short* __restrict__ vT) {
  __shared__ unsigned short t[64][40];
  if (blockIdx.x < 1024) {  // ---- RoPE on shared k ----
    int idx = blockIdx.x * 256 + threadIdx.x;
    int i = idx & 63;
    int bn = idx >> 6;
    int n = bn & (NN - 1);
    unsigned v = *(const unsigned*)(kv + (size_t)bn * 256 + 2 * i);
    float x1 = bf2f((unsigned short)(v & 0xffff));
    float x2 = bf2f((unsigned short)(v >> 16));
    float inv = __expf(-0.14391156831212787f * (float)i);
    float ang = (float)n * inv;
    float sn, cs;
    __sincosf(ang, &sn, &cs);
    float o1 = x1 * cs - x2 * sn, o2 = x1 * sn + x2 * cs;
    unsigned ov = ((unsigned)f2bf(o2) << 16) | f2bf(o1);
    *(unsigned*)(ko + (size_t)bn * DD + 2 * i) = ov;
    return;
  }
  // ---- V transpose: kvb cols 128..255 -> vT[b][d][n] ----
  int bx = blockIdx.x - 1024;  // 256 blocks
  int b = bx >> 7;
  int d0 = ((bx >> 5) & 3) * 32;
  int n0 = (bx & 31) * 64;
  int tid = threadIdx.x;
  {
    int i = tid >> 2;
    int c = (tid & 3) * 8;
    s16x8 v = *(const s16x8*)(kv + ((size_t)(b * NN + n0 + i)) * 256 + 128 + d0 + c);
#pragma unroll
    for (int u = 0; u < 8; ++u) t[i][c + u] = (unsigned short)v[u];
  }
  __syncthreads();
  {
    int j = tid >> 3;
    int cc = (tid & 7) * 8;
    s16x8 o;
#pragma unroll
    for (int u = 0; u < 8; ++u) o[u] = (short)t[cc + u][j];
    *(s16x8*)(vT + ((size_t)(b * DD + d0 + j)) * NN + n0 + cc) = o;
  }
}

// ------- causal flash attention: QB=128, 8 waves, intra-block key-split ------
// R11/R14-proven staging: global_load_lds direct (latency batched per tile).
#define QB 128
#define KB 64

__global__ __launch_bounds__(512, 2) void attn(const unsigned short* __restrict__ Q,
                                               const unsigned short* __restrict__ Kr,
                                               const unsigned short* __restrict__ VT,
                                               const float* __restrict__ KVHP,
                                               unsigned short* __restrict__ O) {
  __shared__ alignas(16) unsigned char Klds[2 * 64 * 256];   // per-parity [key][d]
  __shared__ alignas(16) unsigned char Vlds[2 * 128 * 128];  // per-parity [d][key]
  __shared__ alignas(16) unsigned char Plds[16 * 16 * 128];  // P store; flush: O scratch
  __shared__ float2 mlbuf[4][2][16];

  const int qp = blockIdx.x;
  const int h = blockIdx.y;
  const int b = blockIdx.z;
  const int tid = threadIdx.x;
  const int wave = tid >> 6, lane = tid & 63;
  const int parity = wave >> 2, wq = wave & 3;
  const int g = lane >> 4, lr = lane & 15;
  const size_t bh = (size_t)(b * HH + h);

  const float scale2 = 0.08838834764831845f * 1.4426950408889634f;  // exp2 domain
  const unsigned short* Kb = Kr + (size_t)b * NN * DD;
  const unsigned short* VTb = VT + (size_t)b * DD * NN;
  const float2* KVp = (const float2*)KVHP + (size_t)(b * HH + h) * NN;

  unsigned char* Kl = Klds + parity * (64 * 256);
  unsigned char* Vl = Vlds + parity * (128 * 128);
  float* Obuf = (float*)Plds;

  auto STAGE = [&](int key0s) {
#pragma unroll
    for (int j = 0; j < 4; ++j) {
      int rl = wq * 16 + j * 4 + (lane >> 4);
      int ch = (lane & 15) ^ (rl & 7);
      const unsigned char* gp = (const unsigned char*)(Kb + (size_t)(key0s + rl) * DD) + ch * 16;
      gload_lds16(gp, (void*)(Kl + (wq * 16 + j * 4) * 256));
    }
#pragma unroll
    for (int j = 0; j < 4; ++j) {
      int row = wq * 32 + j * 8 + (lane >> 3);
      int c = lane & 7;
      const unsigned short* gp = VTb + (size_t)row * NN + key0s + ((c ^ (row & 7)) * 8);
      gload_lds16(gp, (void*)(Vl + (wq * 32 + j * 8) * 128));
    }
  };

  auto PHASE = [&](int qt) {
    const int qbase_w = qt * QB + wq * 32;

    s16x8 qf[2][4];
#pragma unroll
    for (int qq = 0; qq < 2; ++qq) {
      const unsigned short* qptr = Q + (bh * NN + qbase_w + qq * 16 + lr) * DD + 8 * g;
#pragma unroll
      for (int dc = 0; dc < 4; ++dc) qf[qq][dc] = *(const s16x8*)(qptr + dc * 32);
    }

    float m_run[2] = {-1e30f, -1e30f}, l_run[2] = {0.f, 0.f};
    fx4 oacc[2][8];
#pragma unroll
    for (int qq = 0; qq < 2; ++qq)
#pragma unroll
      for (int d = 0; d < 8; ++d) oacc[qq][d] = (fx4){0.f, 0.f, 0.f, 0.f};

    const int cnt = qt + 1;
    for (int i = 0; i < cnt; ++i) {
      const int key0 = (2 * i + parity) * KB;
      __syncthreads();
      fx4 khv[4], vhv[4];
#pragma unroll
      for (int kb = 0; kb < 4; ++kb) {
        const float4* kp = (const float4*)(KVp + key0 + kb * 16 + 4 * g);
        float4 f0 = kp[0];
        float4 f1 = kp[1];
        khv[kb] = (fx4){f0.x * scale2, f0.z * scale2, f1.x * scale2, f1.z * scale2};
        vhv[kb] = (fx4){f0.y, f0.w, f1.y, f1.w};
      }
      STAGE(key0);
      __syncthreads();

      if (key0 <= qbase_w + 31) {
        fx4 sacc[2][4];
#pragma unroll
        for (int qq = 0; qq < 2; ++qq)
#pragma unroll
          for (int kb = 0; kb < 4; ++kb) sacc[qq][kb] = (fx4){0.f, 0.f, 0.f, 0.f};
        __builtin_amdgcn_s_setprio(1);
#pragma unroll
        for (int kb = 0; kb < 4; ++kb) {
#pragma unroll
          for (int dc = 0; dc < 4; ++dc) {
            int key = kb * 16 + lr;
            int chunk = (dc * 4 + g) ^ (key & 7);
            s16x8 kf = *(const s16x8*)(Kl + key * 256 + chunk * 16);
            sacc[0][kb] = __builtin_amdgcn_mfma_f32_16x16x32_bf16(kf, qf[0][dc], sacc[0][kb], 0, 0, 0);
            sacc[1][kb] = __builtin_amdgcn_mfma_f32_16x16x32_bf16(kf, qf[1][dc], sacc[1][kb], 0, 0, 0);
          }
        }
        __builtin_amdgcn_s_setprio(0);

#pragma unroll
        for (int qq = 0; qq < 2; ++qq) {
          const int qg = qbase_w + qq * 16 + lr;
          float smax = -1e30f;
          if (key0 + 63 > qbase_w + qq * 16) {
#pragma unroll
            for (int kb = 0; kb < 4; ++kb) {
#pragma unroll
              for (int r = 0; r < 4; ++r) {
                int keyg = key0 + kb * 16 + 4 * g + r;
                float s = sacc[qq][kb][r] * khv[kb][r];
                if (keyg > qg) s = -1e30f;
                sacc[qq][kb][r] = s;
                smax = fmaxf(smax, s);
              }
            }
          } else {
#pragma unroll
            for (int kb = 0; kb < 4; ++kb) {
#pragma unroll
              for (int r = 0; r < 4; ++r) {
                float s = sacc[qq][kb][r] * khv[kb][r];
                sacc[qq][kb][r] = s;
                smax = fmaxf(smax, s);
              }
            }
          }
          smax = fmaxf(smax, __shfl_xor(smax, 16));
          smax = fmaxf(smax, __shfl_xor(smax, 32));
          if (!__all(smax - m_run[qq] <= 8.0f)) {
            float mnew = fmaxf(m_run[qq], smax);
            float corr = exp2f(m_run[qq] - mnew);
            m_run[qq] = mnew;
            l_run[qq] *= corr;
            float cr[4];
#pragma unroll
            for (int r = 0; r < 4; ++r) cr[r] = __shfl(corr, 4 * g + r);
#pragma unroll
            for (int d = 0; d < 8; ++d)
#pragma unroll
              for (int r = 0; r < 4; ++r) oacc[qq][d][r] *= cr[r];
          }
          float rsum = 0.f;
#pragma unroll
          for (int kb = 0; kb < 4; ++kb) {
            float p0 = exp2f(sacc[qq][kb][0] - m_run[qq]);
            float p1 = exp2f(sacc[qq][kb][1] - m_run[qq]);
            float p2 = exp2f(sacc[qq][kb][2] - m_run[qq]);
            float p3 = exp2f(sacc[qq][kb][3] - m_run[qq]);
            rsum += (p0 + p1) + (p2 + p3);
            uint2 w;
            w.x = cvt_pk_bf16(p0 * vhv[kb][0], p1 * vhv[kb][1]);
            w.y = cvt_pk_bf16(p2 * vhv[kb][2], p3 * vhv[kb][3]);
            int chunk = (kb * 2 + (g >> 1)) ^ (lr & 7);
            *(uint2*)(Plds + (wave * 2 + qq) * 2048 + lr * 128 + chunk * 16 + (g & 1) * 8) = w;
          }
          rsum += __shfl_xor(rsum, 16);
          rsum += __shfl_xor(rsum, 32);
          l_run[qq] += rsum;
        }

        s16x8 pa[2][2];
#pragma unroll
        for (int qq = 0; qq < 2; ++qq)
#pragma unroll
          for (int kk = 0; kk < 2; ++kk) {
            int chunk = (kk * 4 + g) ^ (lr & 7);
            pa[qq][kk] = *(const s16x8*)(Plds + (wave * 2 + qq) * 2048 + lr * 128 + chunk * 16);
          }
        __builtin_amdgcn_s_setprio(1);
#pragma unroll
        for (int dc = 0; dc < 8; ++dc) {
#pragma unroll
          for (int kk = 0; kk < 2; ++kk) {
            int d = dc * 16 + lr;
            int chunk = (kk * 4 + g) ^ (d & 7);
            s16x8 vf = *(const s16x8*)(Vl + d * 128 + chunk * 16);
            oacc[0][dc] = __builtin_amdgcn_mfma_f32_16x16x32_bf16(pa[0][kk], vf, oacc[0][dc], 0, 0, 0);
            oacc[1][dc] = __builtin_amdgcn_mfma_f32_16x16x32_bf16(pa[1][kk], vf, oacc[1][dc], 0, 0, 0);
          }
        }
        __builtin_amdgcn_s_setprio(0);
      }
    }

    // ---- combine parities ----
    __syncthreads();
    if (parity == 1 && g == 0) {
#pragma unroll
      for (int qq = 0; qq < 2; ++qq)
        mlbuf[wq][qq][lr] = make_float2(m_run[qq], l_run[qq]);
    }
    __syncthreads();
    float lC[2], af0[2][4], af1[2][4];
    if (parity == 0) {
#pragma unroll
      for (int qq = 0; qq < 2; ++qq) {
        float2 ml1 = mlbuf[wq][qq][lr];
        float M = fmaxf(m_run[qq], ml1.x);
        float a0 = exp2f(m_run[qq] - M);
        float a1 = exp2f(ml1.x - M);
        lC[qq] = l_run[qq] * a0 + ml1.y * a1;
#pragma unroll
        for (int r = 0; r < 4; ++r) {
          af0[qq][r] = __shfl(a0, 4 * g + r);
          af1[qq][r] = __shfl(a1, 4 * g + r);
        }
      }
    }
#pragma unroll
    for (int dh = 0; dh < 2; ++dh) {
      if (parity == 1) {
#pragma unroll
        for (int qq = 0; qq < 2; ++qq)
#pragma unroll
          for (int dc2 = 0; dc2 < 4; ++dc2)
#pragma unroll
            for (int r = 0; r < 4; ++r)
              Obuf[wq * 2048 + (qq * 16 + 4 * g + r) * 64 + dc2 * 16 + lr] =
                  oacc[qq][dh * 4 + dc2][r];
      }
      __syncthreads();
      if (parity == 0) {
#pragma unroll
        for (int qq = 0; qq < 2; ++qq)
#pragma unroll
          for (int dc2 = 0; dc2 < 4; ++dc2)
#pragma unroll
            for (int r = 0; r < 4; ++r) {
              float o1 = Obuf[wq * 2048 + (qq * 16 + 4 * g + r) * 64 + dc2 * 16 + lr];
              oacc[qq][dh * 4 + dc2][r] =
                  oacc[qq][dh * 4 + dc2][r] * af0[qq][r] + o1 * af1[qq][r];
            }
      }
      __syncthreads();
    }
    if (parity == 0) {
#pragma unroll
      for (int qq = 0; qq < 2; ++qq) {
        float inv = 1.0f / lC[qq];
#pragma unroll
        for (int r = 0; r < 4; ++r) {
          float invr = __shfl(inv, 4 * g + r);
          int qout = qbase_w + qq * 16 + 4 * g + r;
          unsigned short* orow = O + (((size_t)b * NN + qout) * HH + h) * DD;
#pragma unroll
          for (int dc = 0; dc < 8; ++dc) orow[dc * 16 + lr] = f2bf(oacc[qq][dc][r] * invr);
        }
      }
    }
  };

  PHASE(qp);
  PHASE(15 - qp);
}

// ---------------- launch -----------------------------------------------------
extern "C" void kernel_launch(void* const* d_in, const int* in_sizes, int n_in,
                              void* d_out, int out_size, void* d_ws, size_t ws_size,
                              hipStream_t stream) {
  const float* x = (const float*)d_in[0];
  const float* Wq = (const float*)d_in[1];
  const float* Wkv = (const float*)d_in[2];
  const float* Wkvh = (const float*)d_in[3];
  const float* Wo = (const float*)d_in[4];
  float* out = (float*)d_out;
  char* ws = (char*)d_ws;

  unsigned short* xb    = (unsigned short*)(ws + 0);          // 16 MB (b*n, E)
  unsigned short* obuf  = xb;                                  // alias: x dead by attn
  unsigned short* wqkv  = (unsigned short*)(ws + 16777216);    // 9.4 MB [Wq;Wkv] bf16
  unsigned short* wob   = (unsigned short*)(ws + 26214400);    // 8 MB
  unsigned short* kvb   = (unsigned short*)(ws + 34603008);    // 2 MB (b*n, 256)
  unsigned short* vtb   = (unsigned short*)(ws + 36700160);    // 1 MB vT[b][d][n]
  unsigned short* wkvhb = (unsigned short*)(ws + 53477376);    // 128 KB Wkvh bf16
  float*          kvhb  = (float*)(ws + 53608448);             // 512 KB packed [b][h][n]{k,v}
  unsigned short* qrope = (unsigned short*)(ws + 54132736);    // 16 MB (b*h, n, d)
  unsigned short* krope = (unsigned short*)(ws + 70909952);    // 1 MB (b*n, d)

  f2b_all<<<16960, 256, 0, stream>>>(x, Wq, Wkv, Wo, Wkvh, xb, wqkv, wob, wkvhb);

  gemm_qkv<<<704, 256, 0, stream>>>(xb, wqkv, wkvhb, qrope, kvb, kvhb, 4096, 2304, 2048);

  rope_vt<<<1280, 256, 0, stream>>>(kvb, krope, vtb);

  dim3 ag(8, HH, BB);
  attn<<<ag, 512, 0, stream>>>(qrope, krope, vtb, kvhb, obuf);

  gemm_out<<<512, 256, 0, stream>>>(obuf, wob, out, 4096, 2048, 2048);
}

// Round 17
// 214.255 us; speedup vs baseline: 1.2551x; 1.0214x over previous
//
#include <hip/hip_runtime.h>
#include <stdint.h>

#define BB 2
#define HH 16
#define NN 2048
#define DD 128
#define EE 2048

typedef short s16x8 __attribute__((ext_vector_type(8)));
typedef float fx4 __attribute__((ext_vector_type(4)));

static __device__ __forceinline__ unsigned short f2bf(float f) {
  unsigned u = __builtin_bit_cast(unsigned, f);
  u += 0x7fffu + ((u >> 16) & 1u);
  return (unsigned short)(u >> 16);
}
static __device__ __forceinline__ float bf2f(unsigned short h) {
  unsigned u = ((unsigned)h) << 16;
  return __builtin_bit_cast(float, u);
}
static __device__ __forceinline__ void gload_lds16(const void* g, void* l) {
  __builtin_amdgcn_global_load_lds(
      (const __attribute__((address_space(1))) unsigned int*)g,
      (__attribute__((address_space(3))) unsigned int*)l, 16, 0, 0);
}
static __device__ __forceinline__ unsigned cvt_pk_bf16(float lo, float hi) {
  unsigned w;
  asm("v_cvt_pk_bf16_f32 %0, %1, %2" : "=v"(w) : "v"(lo), "v"(hi));
  return w;
}

// ---------------- single fp32->bf16 convert for ALL regions ------------------
__global__ __launch_bounds__(256) void f2b_all(const float* __restrict__ x,
                                               const float* __restrict__ Wq,
                                               const float* __restrict__ Wkv,
                                               const float* __restrict__ Wo,
                                               const float* __restrict__ Wkvh,
                                               unsigned short* __restrict__ xb,
                                               unsigned short* __restrict__ wqkv,
                                               unsigned short* __restrict__ wob,
                                               unsigned short* __restrict__ wkvhb) {
  int bid = blockIdx.x;
  const float* in;
  unsigned short* out;
  int i;
  if (bid < 8192) { in = x; out = xb; i = bid * 256 + threadIdx.x; }
  else if (bid < 12288) { in = Wq; out = wqkv; i = (bid - 8192) * 256 + threadIdx.x; }
  else if (bid < 12800) { in = Wkv; out = wqkv + 4194304; i = (bid - 12288) * 256 + threadIdx.x; }
  else if (bid < 16896) { in = Wo; out = wob; i = (bid - 12800) * 256 + threadIdx.x; }
  else { in = Wkvh; out = wkvhb; i = (bid - 16896) * 256 + threadIdx.x; }
  float4 v = ((const float4*)in)[i];
  uint2 o;
  o.x = ((unsigned)f2bf(v.y) << 16) | f2bf(v.x);
  o.y = ((unsigned)f2bf(v.w) << 16) | f2bf(v.z);
  ((uint2*)out)[i] = o;
}

// ====== shared GEMM body: 128x128 tile, BK=64, swizzled staging ==============
#define GBK 64

#define GEMM_STAGE(LDSB, SRCBASE, rowb)                                        \
  _Pragma("unroll") for (int t = 0; t < 4; ++t) {                              \
    int r = wave * 32 + t * 8 + (lane >> 3);                                   \
    int ch = (lane & 7) ^ (r & 7);                                             \
    const unsigned char* src = (SRCBASE) + (size_t)r * (rowb) + ch * 16;       \
    gload_lds16(src, (void*)((LDSB) + (wave * 32 + t * 8) * 128));             \
  }

#define GEMM_LOOP_BODY                                                         \
  for (int k0 = 0; k0 < K; k0 += GBK) {                                        \
    const unsigned char* ag = Ag + (size_t)k0 * 2;                             \
    const unsigned char* bg = Bg + (size_t)k0 * 2;                             \
    __syncthreads();                                                           \
    GEMM_STAGE(Alds, ag, rowb)                                                 \
    GEMM_STAGE(Blds, bg, rowb)                                                 \
    __syncthreads();                                                           \
    _Pragma("unroll") for (int kk = 0; kk < 2; ++kk) {                         \
      s16x8 af[4], bf[4];                                                      \
      _Pragma("unroll") for (int i = 0; i < 4; ++i) {                          \
        int row = wr * 64 + i * 16 + lr;                                       \
        int chunk = (kk * 4 + g) ^ (row & 7);                                  \
        af[i] = *(const s16x8*)(Alds + row * 128 + chunk * 16);                \
      }                                                                        \
      _Pragma("unroll") for (int j = 0; j < 4; ++j) {                          \
        int row = wc * 64 + j * 16 + lr;                                       \
        int chunk = (kk * 4 + g) ^ (row & 7);                                  \
        bf[j] = *(const s16x8*)(Blds + row * 128 + chunk * 16);                \
      }                                                                        \
      _Pragma("unroll") for (int i = 0; i < 4; ++i)                            \
        _Pragma("unroll") for (int j = 0; j < 4; ++j)                          \
          acc[i][j] = __builtin_amdgcn_mfma_f32_16x16x32_bf16(af[i], bf[j],    \
                                                              acc[i][j], 0, 0, 0); \
    }                                                                          \
  }

#define GEMM_PROLOG                                                            \
  __shared__ alignas(16) unsigned char Alds[128 * 128];                        \
  __shared__ alignas(16) unsigned char Blds[128 * 128];                        \
  const int tid = threadIdx.x;                                                 \
  const int wave = tid >> 6, lane = tid & 63;                                  \
  const int g = lane >> 4, lr = lane & 15;                                     \
  const int mtiles = M / 128;                                                  \
  const int mt = blockIdx.x % mtiles, nt = blockIdx.x / mtiles;                \
  const int m0 = mt * 128, n0 = nt * 128;                                      \
  const int wr = wave >> 1, wc = wave & 1;                                     \
  fx4 acc[4][4];                                                               \
  _Pragma("unroll") for (int i = 0; i < 4; ++i)                                \
    _Pragma("unroll") for (int j = 0; j < 4; ++j)                              \
      acc[i][j] = (fx4){0.f, 0.f, 0.f, 0.f};                                   \
  const unsigned char* Ag = (const unsigned char*)(A + (size_t)m0 * K);        \
  const unsigned char* Bg = (const unsigned char*)(B + (size_t)n0 * K);        \
  const size_t rowb = (size_t)K * 2;

// ---------------- out GEMM: fp32 C --------------------------------------------
__global__ __launch_bounds__(256) void gemm_out(const unsigned short* __restrict__ A,
                                                const unsigned short* __restrict__ B,
                                                float* __restrict__ Cf,
                                                int M, int N, int K) {
  GEMM_PROLOG
  GEMM_LOOP_BODY
#pragma unroll
  for (int i = 0; i < 4; ++i) {
    int row = m0 + wr * 64 + i * 16 + 4 * g;
#pragma unroll
    for (int j = 0; j < 4; ++j) {
      int col = n0 + wc * 64 + j * 16 + lr;
#pragma unroll
      for (int r = 0; r < 4; ++r)
        Cf[(size_t)(row + r) * N + col] = acc[i][j][r];
    }
  }
}

// ---------------- qkv GEMM with fused RoPE-q epilogue ------------------------
__global__ __launch_bounds__(256) void gemm_qkv(const unsigned short* __restrict__ A,
                                                const unsigned short* __restrict__ B,
                                                unsigned short* __restrict__ qrope,
                                                unsigned short* __restrict__ kvb,
                                                int M, int N, int K) {
  GEMM_PROLOG
  GEMM_LOOP_BODY
#pragma unroll
  for (int j = 0; j < 4; ++j) {
    int col = n0 + wc * 64 + j * 16 + lr;
    if (col < 2048) {
      int hh = col >> 7, d = col & 127;
      float invf = __expf(-0.14391156831212787f * (float)(d >> 1));
      int par = d & 1;
#pragma unroll
      for (int i = 0; i < 4; ++i) {
#pragma unroll
        for (int r = 0; r < 4; ++r) {
          int row = m0 + wr * 64 + i * 16 + 4 * g + r;
          int n = row & (NN - 1), bq = row >> 11;
          float self = acc[i][j][r];
          float other = __shfl_xor(self, 1);
          float sn, cs;
          __sincosf((float)n * invf, &sn, &cs);
          float a = self * cs, bt = other * sn;
          float o = par ? (a + bt) : (a - bt);
          qrope[((size_t)(bq * HH + hh) * NN + n) * DD + d] = f2bf(o);
        }
      }
    } else {
      int c2 = col - 2048;
#pragma unroll
      for (int i = 0; i < 4; ++i) {
#pragma unroll
        for (int r = 0; r < 4; ++r) {
          int row = m0 + wr * 64 + i * 16 + 4 * g + r;
          kvb[(size_t)row * 256 + c2] = f2bf(acc[i][j][r]);
        }
      }
    }
  }
}

// ---------------- kvh projection via MFMA -> packed [b][h][n]{k,v} ----------
__global__ __launch_bounds__(256) void kvh_mfma(const unsigned short* __restrict__ X,
                                                const unsigned short* __restrict__ Wb,
                                                float* __restrict__ out) {
  const int tid = threadIdx.x;
  const int wave = tid >> 6, lane = tid & 63;
  const int g = lane >> 4, lr = lane & 15;
  const int rowbase = blockIdx.x * 32 + (wave & 1) * 16;
  const int colbase = (wave >> 1) * 16;

  const unsigned short* xr = X + (size_t)(rowbase + lr) * EE + 8 * g;
  const unsigned short* wr = Wb + (size_t)(colbase + lr) * EE + 8 * g;

  fx4 acc = (fx4){0.f, 0.f, 0.f, 0.f};
#pragma unroll 8
  for (int k0 = 0; k0 < EE; k0 += 32) {
    s16x8 a = *(const s16x8*)(xr + k0);
    s16x8 b = *(const s16x8*)(wr + k0);
    acc = __builtin_amdgcn_mfma_f32_16x16x32_bf16(a, b, acc, 0, 0, 0);
  }
  const int j = colbase + lr;
  const int head = j & 15, sel = j >> 4;
#pragma unroll
  for (int r = 0; r < 4; ++r) {
    int m = rowbase + 4 * g + r;
    int b = m >> 11, n = m & (NN - 1);
    out[(((size_t)(b * HH + head)) * NN + n) * 2 + sel] = acc[r];
  }
}

// ---------------- RoPE on shared k (kvb rows stride 256, cols 0..127) --------
__global__ __launch_bounds__(256) void rope_k(const unsigned short* __restrict__ kv,
                                              unsigned short* __restrict__ ko) {
  int idx = blockIdx.x * 256 + threadIdx.x;
  int i = idx & 63;
  int bn = idx >> 6;
  int n = bn & (NN - 1);
  unsigned v = *(const unsigned*)(kv + (size_t)bn * 256 + 2 * i);
  float x1 = bf2f((unsigned short)(v & 0xffff));
  float x2 = bf2f((unsigned short)(v >> 16));
  float inv = __expf(-0.14391156831212787f * (float)i);
  float ang = (float)n * inv;
  float sn, cs;
  __sincosf(ang, &sn, &cs);
  float o1 = x1 * cs - x2 * sn, o2 = x1 * sn + x2 * cs;
  unsigned ov = ((unsigned)f2bf(o2) << 16) | f2bf(o1);
  *(unsigned*)(ko + (size_t)bn * DD + 2 * i) = ov;
}

// ---------------- V transpose: kvb cols 128..255 -> vT[b][d][n] --------------
__global__ __launch_bounds__(256) void vtrans(const unsigned short* __restrict__ kv,
                                              unsigned short* __restrict__ vT) {
  __shared__ unsigned short t[64][40];
  int bx = blockIdx.x;  // 2*4*32 = 256 blocks
  int b = bx >> 7;
  int d0 = ((bx >> 5) & 3) * 32;
  int n0 = (bx & 31) * 64;
  int tid = threadIdx.x;
  {
    int i = tid >> 2;
    int c = (tid & 3) * 8;
    s16x8 v = *(const s16x8*)(kv + ((size_t)(b * NN + n0 + i)) * 256 + 128 + d0 + c);
#pragma unroll
    for (int u = 0; u < 8; ++u) t[i][c + u] = (unsigned short)v[u];
  }
  __syncthreads();
  {
    int j = tid >> 3;
    int cc = (tid & 7) * 8;
    s16x8 o;
#pragma unroll
    for (int u = 0; u < 8; ++u) o[u] = (short)t[cc + u][j];
    *(s16x8*)(vT + ((size_t)(b * DD + d0 + j)) * NN + n0 + cc) = o;
  }
}

// ------- causal flash attention: QB=128, 8 waves, intra-block key-split ------
// R11-proven staging: global_load_lds direct (no reg round-trip, no spills).
#define QB 128
#define KB 64

__global__ __launch_bounds__(512, 2) void attn(const unsigned short* __restrict__ Q,
                                               const unsigned short* __restrict__ Kr,
                                               const unsigned short* __restrict__ VT,
                                               const float* __restrict__ KVHP,
                                               unsigned short* __restrict__ O) {
  __shared__ alignas(16) unsigned char Klds[2 * 64 * 256];   // per-parity [key][d]
  __shared__ alignas(16) unsigned char Vlds[2 * 128 * 128];  // per-parity [d][key]
  __shared__ alignas(16) unsigned char Plds[16 * 16 * 128];  // P store; flush: O scratch
  __shared__ float2 mlbuf[4][2][16];

  const int qp = blockIdx.x;
  const int h = blockIdx.y;
  const int b = blockIdx.z;
  const int tid = threadIdx.x;
  const int wave = tid >> 6, lane = tid & 63;
  const int parity = wave >> 2, wq = wave & 3;
  const int g = lane >> 4, lr = lane & 15;
  const size_t bh = (size_t)(b * HH + h);

  const float scale2 = 0.08838834764831845f * 1.4426950408889634f;  // exp2 domain
  const unsigned short* Kb = Kr + (size_t)b * NN * DD;
  const unsigned short* VTb = VT + (size_t)b * DD * NN;
  const float2* KVp = (const float2*)KVHP + (size_t)(b * HH + h) * NN;

  unsigned char* Kl = Klds + parity * (64 * 256);
  unsigned char* Vl = Vlds + parity * (128 * 128);
  float* Obuf = (float*)Plds;

  auto STAGE = [&](int key0s) {
#pragma unroll
    for (int j = 0; j < 4; ++j) {
      int rl = wq * 16 + j * 4 + (lane >> 4);
      int ch = (lane & 15) ^ (rl & 7);
      const unsigned char* gp = (const unsigned char*)(Kb + (size_t)(key0s + rl) * DD) + ch * 16;
      gload_lds16(gp, (void*)(Kl + (wq * 16 + j * 4) * 256));
    }
#pragma unroll
    for (int j = 0; j < 4; ++j) {
      int row = wq * 32 + j * 8 + (lane >> 3);
      int c = lane & 7;
      const unsigned short* gp = VTb + (size_t)row * NN + key0s + ((c ^ (row & 7)) * 8);
      gload_lds16(gp, (void*)(Vl + (wq * 32 + j * 8) * 128));
    }
  };

  auto PHASE = [&](int qt) {
    const int qbase_w = qt * QB + wq * 32;

    s16x8 qf[2][4];
#pragma unroll
    for (int qq = 0; qq < 2; ++qq) {
      const unsigned short* qptr = Q + (bh * NN + qbase_w + qq * 16 + lr) * DD + 8 * g;
#pragma unroll
      for (int dc = 0; dc < 4; ++dc) qf[qq][dc] = *(const s16x8*)(qptr + dc * 32);
    }

    float m_run[2] = {-1e30f, -1e30f}, l_run[2] = {0.f, 0.f};
    fx4 oacc[2][8];
#pragma unroll
    for (int qq = 0; qq < 2; ++qq)
#pragma unroll
      for (int d = 0; d < 8; ++d) oacc[qq][d] = (fx4){0.f, 0.f, 0.f, 0.f};

    const int cnt = qt + 1;
    for (int i = 0; i < cnt; ++i) {
      const int key0 = (2 * i + parity) * KB;
      __syncthreads();
      fx4 khv[4], vhv[4];
#pragma unroll
      for (int kb = 0; kb < 4; ++kb) {
        const float4* kp = (const float4*)(KVp + key0 + kb * 16 + 4 * g);
        float4 f0 = kp[0];
        float4 f1 = kp[1];
        khv[kb] = (fx4){f0.x * scale2, f0.z * scale2, f1.x * scale2, f1.z * scale2};
        vhv[kb] = (fx4){f0.y, f0.w, f1.y, f1.w};
      }
      STAGE(key0);
      __syncthreads();

      if (key0 <= qbase_w + 31) {
        fx4 sacc[2][4];
#pragma unroll
        for (int qq = 0; qq < 2; ++qq)
#pragma unroll
          for (int kb = 0; kb < 4; ++kb) sacc[qq][kb] = (fx4){0.f, 0.f, 0.f, 0.f};
        __builtin_amdgcn_s_setprio(1);
#pragma unroll
        for (int kb = 0; kb < 4; ++kb) {
#pragma unroll
          for (int dc = 0; dc < 4; ++dc) {
            int key = kb * 16 + lr;
            int chunk = (dc * 4 + g) ^ (key & 7);
            s16x8 kf = *(const s16x8*)(Kl + key * 256 + chunk * 16);
            sacc[0][kb] = __builtin_amdgcn_mfma_f32_16x16x32_bf16(kf, qf[0][dc], sacc[0][kb], 0, 0, 0);
            sacc[1][kb] = __builtin_amdgcn_mfma_f32_16x16x32_bf16(kf, qf[1][dc], sacc[1][kb], 0, 0, 0);
          }
        }
        __builtin_amdgcn_s_setprio(0);

#pragma unroll
        for (int qq = 0; qq < 2; ++qq) {
          const int qg = qbase_w + qq * 16 + lr;
          float smax = -1e30f;
          if (key0 + 63 > qbase_w + qq * 16) {
#pragma unroll
            for (int kb = 0; kb < 4; ++kb) {
#pragma unroll
              for (int r = 0; r < 4; ++r) {
                int keyg = key0 + kb * 16 + 4 * g + r;
                float s = sacc[qq][kb][r] * khv[kb][r];
                if (keyg > qg) s = -1e30f;
                sacc[qq][kb][r] = s;
                smax = fmaxf(smax, s);
              }
            }
          } else {
#pragma unroll
            for (int kb = 0; kb < 4; ++kb) {
#pragma unroll
              for (int r = 0; r < 4; ++r) {
                float s = sacc[qq][kb][r] * khv[kb][r];
                sacc[qq][kb][r] = s;
                smax = fmaxf(smax, s);
              }
            }
          }
          smax = fmaxf(smax, __shfl_xor(smax, 16));
          smax = fmaxf(smax, __shfl_xor(smax, 32));
          if (!__all(smax - m_run[qq] <= 8.0f)) {
            float mnew = fmaxf(m_run[qq], smax);
            float corr = exp2f(m_run[qq] - mnew);
            m_run[qq] = mnew;
            l_run[qq] *= corr;
            float cr[4];
#pragma unroll
            for (int r = 0; r < 4; ++r) cr[r] = __shfl(corr, 4 * g + r);
#pragma unroll
            for (int d = 0; d < 8; ++d)
#pragma unroll
              for (int r = 0; r < 4; ++r) oacc[qq][d][r] *= cr[r];
          }
          float rsum = 0.f;
#pragma unroll
          for (int kb = 0; kb < 4; ++kb) {
            float p0 = exp2f(sacc[qq][kb][0] - m_run[qq]);
            float p1 = exp2f(sacc[qq][kb][1] - m_run[qq]);
            float p2 = exp2f(sacc[qq][kb][2] - m_run[qq]);
            float p3 = exp2f(sacc[qq][kb][3] - m_run[qq]);
            rsum += (p0 + p1) + (p2 + p3);
            uint2 w;
            w.x = cvt_pk_bf16(p0 * vhv[kb][0], p1 * vhv[kb][1]);
            w.y = cvt_pk_bf16(p2 * vhv[kb][2], p3 * vhv[kb][3]);
            int chunk = (kb * 2 + (g >> 1)) ^ (lr & 7);
            *(uint2*)(Plds + (wave * 2 + qq) * 2048 + lr * 128 + chunk * 16 + (g & 1) * 8) = w;
          }
          rsum += __shfl_xor(rsum, 16);
          rsum += __shfl_xor(rsum, 32);
          l_run[qq] += rsum;
        }

        s16x8 pa[2][2];
#pragma unroll
        for (int qq = 0; qq < 2; ++qq)
#pragma unroll
          for (int kk = 0; kk < 2; ++kk) {
            int chunk = (kk * 4 + g) ^ (lr & 7);
            pa[qq][kk] = *(const s16x8*)(Plds + (wave * 2 + qq) * 2048 + lr * 128 + chunk * 16);
          }
        __builtin_amdgcn_s_setprio(1);
#pragma unroll
        for (int dc = 0; dc < 8; ++dc) {
#pragma unroll
          for (int kk = 0; kk < 2; ++kk) {
            int d = dc * 16 + lr;
            int chunk = (kk * 4 + g) ^ (d & 7);
            s16x8 vf = *(const s16x8*)(Vl + d * 128 + chunk * 16);
            oacc[0][dc] = __builtin_amdgcn_mfma_f32_16x16x32_bf16(pa[0][kk], vf, oacc[0][dc], 0, 0, 0);
            oacc[1][dc] = __builtin_amdgcn_mfma_f32_16x16x32_bf16(pa[1][kk], vf, oacc[1][dc], 0, 0, 0);
          }
        }
        __builtin_amdgcn_s_setprio(0);
      }
    }

    // ---- combine parities ----
    __syncthreads();
    if (parity == 1 && g == 0) {
#pragma unroll
      for (int qq = 0; qq < 2; ++qq)
        mlbuf[wq][qq][lr] = make_float2(m_run[qq], l_run[qq]);
    }
    __syncthreads();
    float lC[2], af0[2][4], af1[2][4];
    if (parity == 0) {
#pragma unroll
      for (int qq = 0; qq < 2; ++qq) {
        float2 ml1 = mlbuf[wq][qq][lr];
        float M = fmaxf(m_run[qq], ml1.x);
        float a0 = exp2f(m_run[qq] - M);
        float a1 = exp2f(ml1.x - M);
        lC[qq] = l_run[qq] * a0 + ml1.y * a1;
#pragma unroll
        for (int r = 0; r < 4; ++r) {
          af0[qq][r] = __shfl(a0, 4 * g + r);
          af1[qq][r] = __shfl(a1, 4 * g + r);
        }
      }
    }
#pragma unroll
    for (int dh = 0; dh < 2; ++dh) {
      if (parity == 1) {
#pragma unroll
        for (int qq = 0; qq < 2; ++qq)
#pragma unroll
          for (int dc2 = 0; dc2 < 4; ++dc2)
#pragma unroll
            for (int r = 0; r < 4; ++r)
              Obuf[wq * 2048 + (qq * 16 + 4 * g + r) * 64 + dc2 * 16 + lr] =
                  oacc[qq][dh * 4 + dc2][r];
      }
      __syncthreads();
      if (parity == 0) {
#pragma unroll
        for (int qq = 0; qq < 2; ++qq)
#pragma unroll
          for (int dc2 = 0; dc2 < 4; ++dc2)
#pragma unroll
            for (int r = 0; r < 4; ++r) {
              float o1 = Obuf[wq * 2048 + (qq * 16 + 4 * g + r) * 64 + dc2 * 16 + lr];
              oacc[qq][dh * 4 + dc2][r] =
                  oacc[qq][dh * 4 + dc2][r] * af0[qq][r] + o1 * af1[qq][r];
            }
      }
      __syncthreads();
    }
    if (parity == 0) {
#pragma unroll
      for (int qq = 0; qq < 2; ++qq) {
        float inv = 1.0f / lC[qq];
#pragma unroll
        for (int r = 0; r < 4; ++r) {
          float invr = __shfl(inv, 4 * g + r);
          int qout = qbase_w + qq * 16 + 4 * g + r;
          unsigned short* orow = O + (((size_t)b * NN + qout) * HH + h) * DD;
#pragma unroll
          for (int dc = 0; dc < 8; ++dc) orow[dc * 16 + lr] = f2bf(oacc[qq][dc][r] * invr);
        }
      }
    }
  };

  PHASE(qp);
  PHASE(15 - qp);
}

// ---------------- launch -----------------------------------------------------
extern "C" void kernel_launch(void* const* d_in, const int* in_sizes, int n_in,
                              void* d_out, int out_size, void* d_ws, size_t ws_size,
                              hipStream_t stream) {
  const float* x = (const float*)d_in[0];
  const float* Wq = (const float*)d_in[1];
  const float* Wkv = (const float*)d_in[2];
  const float* Wkvh = (const float*)d_in[3];
  const float* Wo = (const float*)d_in[4];
  float* out = (float*)d_out;
  char* ws = (char*)d_ws;

  unsigned short* xb    = (unsigned short*)(ws + 0);          // 16 MB (b*n, E)
  unsigned short* obuf  = xb;                                  // alias: x dead by attn
  unsigned short* wqkv  = (unsigned short*)(ws + 16777216);    // 9.4 MB [Wq;Wkv] bf16
  unsigned short* wob   = (unsigned short*)(ws + 26214400);    // 8 MB
  unsigned short* kvb   = (unsigned short*)(ws + 34603008);    // 2 MB (b*n, 256)
  unsigned short* vtb   = (unsigned short*)(ws + 36700160);    // 1 MB vT[b][d][n]
  unsigned short* wkvhb = (unsigned short*)(ws + 53477376);    // 128 KB Wkvh bf16
  float*          kvhb  = (float*)(ws + 53608448);             // 512 KB packed [b][h][n]{k,v}
  unsigned short* qrope = (unsigned short*)(ws + 54132736);    // 16 MB (b*h, n, d)
  unsigned short* krope = (unsigned short*)(ws + 70909952);    // 1 MB (b*n, d)

  f2b_all<<<16960, 256, 0, stream>>>(x, Wq, Wkv, Wo, Wkvh, xb, wqkv, wob, wkvhb);

  gemm_qkv<<<576, 256, 0, stream>>>(xb, wqkv, qrope, kvb, 4096, 2304, 2048);
  kvh_mfma<<<128, 256, 0, stream>>>(xb, wkvhb, kvhb);

  rope_k<<<1024, 256, 0, stream>>>(kvb, krope);
  vtrans<<<256, 256, 0, stream>>>(kvb, vtb);

  dim3 ag(8, HH, BB);
  attn<<<ag, 512, 0, stream>>>(qrope, krope, vtb, kvhb, obuf);

  gemm_out<<<512, 256, 0, stream>>>(obuf, wob, out, 4096, 2048, 2048);
}